// Round 8
// baseline (214.653 us; speedup 1.0000x reference)
//
#include <hip/hip_runtime.h>

// 1 - alpha = (1 + exp(density+shift))^(-0.5) = rsqrt(u), u = 1 + exp(x).
// w_k = T_excl * alpha_k,  T_excl accumulated as product of (1-alpha).

__device__ __forceinline__ float fast_sigmoid(float x) {
    return __builtin_amdgcn_rcpf(1.0f + __expf(-x));
}

struct __align__(4) f3  { float x, y, z; };     // 12B, 4B-aligned
struct __align__(4) f4s { float x, y, z, w; };  // 16B, 4B-aligned -> dwordx4

// ---- DPP wave64 scans ------------------------------------------------------
#define DPP_ADD(x, ctrl, rmask)                                               \
    do {                                                                      \
        int _s = __builtin_amdgcn_update_dpp(0, __float_as_int(x), (ctrl),    \
                                             (rmask), 0xf, true);             \
        (x) += __int_as_float(_s);                                            \
    } while (0)

#define DPP_MUL(x, ctrl, rmask)                                               \
    do {                                                                      \
        int _s = __builtin_amdgcn_update_dpp(0x3f800000, __float_as_int(x),   \
                                             (ctrl), (rmask), 0xf, false);    \
        (x) *= __int_as_float(_s);                                            \
    } while (0)

// Inclusive scans SEGMENTED at the lane-31/32 boundary (verified in R3):
// stages row_shr:1/2/4/8 + row_bcast:15 (rows 1,3) never cross 32-lane halves.
__device__ __forceinline__ float half_scan_mul(float x) {
    DPP_MUL(x, 0x111, 0xf);
    DPP_MUL(x, 0x112, 0xf);
    DPP_MUL(x, 0x114, 0xf);
    DPP_MUL(x, 0x118, 0xf);
    DPP_MUL(x, 0x142, 0xa);
    return x;
}
__device__ __forceinline__ float half_scan_add(float x) {
    DPP_ADD(x, 0x111, 0xf);
    DPP_ADD(x, 0x112, 0xf);
    DPP_ADD(x, 0x114, 0xf);
    DPP_ADD(x, 0x118, 0xf);
    DPP_ADD(x, 0x142, 0xa);
    return x;
}

__device__ __forceinline__ float bperm_f(int lane, float v) {
    return __int_as_float(
        __builtin_amdgcn_ds_bpermute(lane * 4, __float_as_int(v)));
}

// ---- Pass 1: segment starts (int4-vectorized boundary detection) -----------
__global__ __launch_bounds__(256) void seg_starts4_kernel(
    const int4* __restrict__ ray4, int M4, int M, int N,
    const int* __restrict__ ray_id, int* __restrict__ starts)
{
    const int i = blockIdx.x * blockDim.x + threadIdx.x;
    if (i >= M4) return;
    const int4 v = ray4[i];
    const int prev = (i == 0) ? -1 : ray_id[4 * i - 1];
    const int base = 4 * i;
    for (int r = prev + 1; r <= v.x; ++r) starts[r] = base;
    for (int r = v.x + 1;  r <= v.y; ++r) starts[r] = base + 1;
    for (int r = v.y + 1;  r <= v.z; ++r) starts[r] = base + 2;
    for (int r = v.z + 1;  r <= v.w; ++r) starts[r] = base + 3;
    if (i == M4 - 1) {
        int last = v.w;
        for (int j = 4 * M4; j < M; ++j) {      // scalar tail (M%4)
            const int cur = ray_id[j];
            for (int r = last + 1; r <= cur; ++r) starts[r] = j;
            last = cur;
        }
        for (int r = last + 1; r <= N; ++r) starts[r] = M;
    }
}

// ---- Pass 2: ray = 32-lane half, 4 samples/lane = FLOAT4 STREAMING ---------
// R0-R7 falsified every scheduling/work lever: render pinned at ~60us,
// 1.78 TB/s, across VALU work +-33%, pinning, ILP depth, occupancy 42-70%.
// The one constant: 4-12B/lane loads. Measured law (G13/m13): sustained BW
// scales with bytes/lane/instruction; 6.3 TB/s needs the 16B/lane regime.
// Here: lane owns 4 CONTIGUOUS samples -> density dwordx4, rgb 3x dwordx4
// (4 samples x 3ch = lane's own 48B, zero redistribution), weights store
// dwordx4. VMEM instrs/wave 16 -> 5, all 16B/lane. 128 slots/ray covers
// max len ~103; half-segmented scan (R3-verified) + bpermute exclusive.
#define RPW 2

__global__ __launch_bounds__(256, 4) void favor_render_kernel(
    const float* __restrict__ density,
    const float* __restrict__ rgb_feat,   // [M,3]
    const float* __restrict__ shift,      // [1]
    const int*   __restrict__ starts,     // [N+1]
    int M, int N,
    float* __restrict__ weights,          // [M]
    float* __restrict__ alphainv_last,    // [N]
    float* __restrict__ out3)             // [N,3]
{
    const int wave = (blockIdx.x * blockDim.x + threadIdx.x) >> 6;
    const int t    = threadIdx.x & 63;
    const int r0   = wave * RPW;
    if (r0 >= N) return;

    const int bv = starts[min(r0 + t, N)];
    const int s0 = __builtin_amdgcn_readlane(bv, 0);
    const int s1 = __builtin_amdgcn_readlane(bv, 1);
    const int s2 = __builtin_amdgcn_readlane(bv, 2);

    const int  half = t >> 5;            // 0: ray r0, 1: ray r0+1
    const int  r    = t & 31;
    const int  st   = half ? s1 : s0;
    const int  en   = half ? s2 : s1;
    const int  len0 = s1 - s0, len1 = s2 - s1;

    const float sh = shift[0];
    // Uniform (scalar) guard: only the last wave(s) can have f4 reads that
    // run past the end of density/rgb_feat; they take per-sample clamped loads.
    const bool unsafe_tail = (s2 > M - 4);

    float carry = 1.0f, accR = 0.0f, accG = 0.0f, accB = 0.0f;
    int off = 0;

    do {
        const int i0 = st + off + 4 * r;

        float d0, d1, d2, d3;
        f3 c0, c1, c2, c3;
        if (unsafe_tail) {                       // last wave only
            const int k0 = max(min(i0,     en - 1), 0);
            const int k1 = max(min(i0 + 1, en - 1), 0);
            const int k2 = max(min(i0 + 2, en - 1), 0);
            const int k3 = max(min(i0 + 3, en - 1), 0);
            d0 = density[k0]; d1 = density[k1];
            d2 = density[k2]; d3 = density[k3];
            c0 = *(const f3*)(rgb_feat + 3 * k0);
            c1 = *(const f3*)(rgb_feat + 3 * k1);
            c2 = *(const f3*)(rgb_feat + 3 * k2);
            c3 = *(const f3*)(rgb_feat + 3 * k3);
        } else {
            // Fully-invalid lanes clamp the base (values masked later);
            // partially-valid lanes load at i0 (reads spill into the next
            // ray's region: in-bounds, masked). Safe: en <= M-4 here.
            const int b  = (i0 < en) ? i0 : max(en - 4, 0);
            const f4s dv = *(const f4s*)(density + b);
            const f4s q0 = *(const f4s*)(rgb_feat + 3 * b);
            const f4s q1 = *(const f4s*)(rgb_feat + 3 * b + 4);
            const f4s q2 = *(const f4s*)(rgb_feat + 3 * b + 8);
            d0 = dv.x; d1 = dv.y; d2 = dv.z; d3 = dv.w;
            c0.x = q0.x; c0.y = q0.y; c0.z = q0.z;
            c1.x = q0.w; c1.y = q1.x; c1.z = q1.y;
            c2.x = q1.z; c2.y = q1.w; c2.z = q2.x;
            c3.x = q2.y; c3.y = q2.z; c3.z = q2.w;
        }

        const bool v0 = (i0     < en), v1 = (i0 + 1 < en);
        const bool v2 = (i0 + 2 < en), v3 = (i0 + 3 < en);

        const float u0 = 1.0f + __expf(d0 + sh);
        const float u1 = 1.0f + __expf(d1 + sh);
        const float u2 = 1.0f + __expf(d2 + sh);
        const float u3 = 1.0f + __expf(d3 + sh);
        const float a0 = v0 ? __builtin_amdgcn_rsqf(u0) : 1.0f;
        const float a1 = v1 ? __builtin_amdgcn_rsqf(u1) : 1.0f;
        const float a2 = v2 ? __builtin_amdgcn_rsqf(u2) : 1.0f;
        const float a3 = v3 ? __builtin_amdgcn_rsqf(u3) : 1.0f;

        const float m = (a0 * a1) * (a2 * a3);   // lane's 4-sample product
        const float S = half_scan_mul(m);        // inclusive over 32-lane half
        float E = bperm_f((t + 63) & 63, S);     // previous lane's inclusive
        E = (r == 0) ? 1.0f : E;                 // half-head identity
        const float tot = bperm_f(t | 31, S);    // half total -> all lanes

        float p = carry * E;                     // T before sample i0
        const float w0 = p * (1.0f - a0); p *= a0;
        const float w1 = p * (1.0f - a1); p *= a1;
        const float w2 = p * (1.0f - a2); p *= a2;
        const float w3 = p * (1.0f - a3);

        accR += w0 * fast_sigmoid(c0.x) + w1 * fast_sigmoid(c1.x)
              + w2 * fast_sigmoid(c2.x) + w3 * fast_sigmoid(c3.x);
        accG += w0 * fast_sigmoid(c0.y) + w1 * fast_sigmoid(c1.y)
              + w2 * fast_sigmoid(c2.y) + w3 * fast_sigmoid(c3.y);
        accB += w0 * fast_sigmoid(c0.z) + w1 * fast_sigmoid(c1.z)
              + w2 * fast_sigmoid(c2.z) + w3 * fast_sigmoid(c3.z);

        if (v3) {                                // all 4 valid: one dwordx4
            f4s wv; wv.x = w0; wv.y = w1; wv.z = w2; wv.w = w3;
            *(f4s*)(weights + i0) = wv;
        } else {                                 // boundary lane of the ray
            if (v0) weights[i0]     = w0;
            if (v1) weights[i0 + 1] = w1;
            if (v2) weights[i0 + 2] = w2;
        }

        carry *= tot;
        off += 128;
    } while (len0 > off || len1 > off);          // uniform; ~never loops

    // ---- epilogue: 3 half-scan-adds cover BOTH rays at once ----
    accR = half_scan_add(accR);
    accG = half_scan_add(accG);
    accB = half_scan_add(accB);
    if ((t & 31) == 31) {                        // lane 31 -> ray r0, 63 -> r0+1
        const int ray = r0 + half;
        if (ray < N) {
            alphainv_last[ray] = carry;
            f3 o;
            o.x = accR + carry; o.y = accG + carry; o.z = accB + carry;
            *(f3*)(out3 + 3 * ray) = o;
        }
    }
}

extern "C" void kernel_launch(void* const* d_in, const int* in_sizes, int n_in,
                              void* d_out, int out_size, void* d_ws, size_t ws_size,
                              hipStream_t stream) {
    const float* density  = (const float*)d_in[0];
    const float* rgb_feat = (const float*)d_in[1];
    const float* shift    = (const float*)d_in[2];
    const int*   ray_id   = (const int*)d_in[3];

    const int M = in_sizes[0];
    const int N = (out_size - M) / 4;   // out_size = M + N + 3N

    float* weights       = (float*)d_out;
    float* alphainv_last = weights + M;
    float* out3          = alphainv_last + N;

    const int block = 256;
    int* starts = (int*)d_ws;

    const int M4 = M >> 2;
    const int grid_starts = (M4 + block - 1) / block;
    seg_starts4_kernel<<<grid_starts, block, 0, stream>>>(
        (const int4*)ray_id, M4, M, N, ray_id, starts);

    const int n_waves = (N + RPW - 1) / RPW;
    const int grid_render = (n_waves * 64 + block - 1) / block;
    favor_render_kernel<<<grid_render, block, 0, stream>>>(
        density, rgb_feat, shift, starts, M, N,
        weights, alphainv_last, out3);
}